// Round 14
// baseline (106.525 us; speedup 1.0000x reference)
//
#include <hip/hip_runtime.h>
#include <cfloat>

#define LAT_ROWS 32768
#define DIM 512
#define KCODES 1024

constexpr int BM = 64;             // latent rows per block
constexpr int BN = 256;            // codes per ct-tile
constexpr int NT = 512;            // 8 waves: 4 code-groups x 2 row-groups
constexpr int NCT = 4;
constexpr int NDK = 8;
constexpr int TT = NCT * NDK;      // 32

// workspace layout (bytes)
constexpr size_t WS_LSUM = 0;                      // 64 doubles
constexpr size_t WS_NORM = 512;                    // 1024 f32
constexpr size_t WS_CBF8 = 4608;                   // 512 KB fp8 fragment-linear
constexpr size_t WS_NEEDED = WS_CBF8 + 65536 * 8;  // ~530 KB

typedef float f32x4 __attribute__((ext_vector_type(4)));
typedef float fx4 __attribute__((ext_vector_type(4)));
typedef short bf16x8 __attribute__((ext_vector_type(8)));
typedef unsigned short u16;
typedef u16 u16x8 __attribute__((ext_vector_type(8)));

__device__ __forceinline__ u16 f2bf(float f) {  // RNE (fallback path)
  unsigned u = __float_as_uint(f);
  u += 0x7FFF + ((u >> 16) & 1);
  return (u16)(u >> 16);
}

// pack 8 f32 -> 8 fp8 e4m3 (RNE) as one 8-byte value
__device__ __forceinline__ long pk8_fp8l(const float4 a, const float4 c) {
  int lo = __builtin_amdgcn_cvt_pk_fp8_f32(a.x, a.y, 0, false);
  lo = __builtin_amdgcn_cvt_pk_fp8_f32(a.z, a.w, lo, true);
  int hi = __builtin_amdgcn_cvt_pk_fp8_f32(c.x, c.y, 0, false);
  hi = __builtin_amdgcn_cvt_pk_fp8_f32(c.z, c.w, hi, true);
  return ((long)(unsigned)hi << 32) | (unsigned)lo;
}
__device__ __forceinline__ long pk8_fp8v(const fx4 a, const fx4 c) {
  int lo = __builtin_amdgcn_cvt_pk_fp8_f32(a.x, a.y, 0, false);
  lo = __builtin_amdgcn_cvt_pk_fp8_f32(a.z, a.w, lo, true);
  int hi = __builtin_amdgcn_cvt_pk_fp8_f32(c.x, c.y, 0, false);
  hi = __builtin_amdgcn_cvt_pk_fp8_f32(c.z, c.w, hi, true);
  return ((long)(unsigned)hi << 32) | (unsigned)lo;
}

// LDS X-image swizzle: permute the l15 field by (4*l4 + 2*ks + (dk&1)).
// unit u = dk*512 + wn*256 + nf*128 + ks*64 + l4*16 + l15
__device__ __forceinline__ constexpr int xswz(int u) {
  const int add = ((u >> 2) & 12) + ((u >> 5) & 2) + ((u >> 9) & 1);
  return (u & ~15) | ((u + add) & 15);
}

// ------------- prep: CB -> fp8 fragment-linear units + norms -------------
// CBf8 idx = (ct*8+dk)*2048 + wm*512 + mf*128 + ks*64 + l4*16 + l15
// content: code = ct*256 + wm*64 + mf*16 + l15, dims d0 = dk*64 + (ks*4+l4)*8
__global__ void __launch_bounds__(NT)
vq_prep15(const float* __restrict__ CB, long* __restrict__ CBf8,
          float* __restrict__ norms) {
  const int bb = blockIdx.x;
  const int tid = threadIdx.x;
  if (bb < 128) {  // ---- CB convert (65536 units)
    const int id = bb * NT + tid;
    const int t = id >> 11;
    const int r = id & 2047;
    const int wm = r >> 9, mf = (r >> 7) & 3, ks = (r >> 6) & 1,
              l4 = (r >> 4) & 3, l15 = id & 15;
    const int ct = t >> 3, dk = t & 7;
    const int code = ct * BN + wm * 64 + mf * 16 + l15;
    const int d0 = dk * 64 + (ks * 4 + l4) * 8;
    const float* src = CB + (size_t)code * DIM + d0;
    const float4 a = *(const float4*)src;
    const float4 c = *(const float4*)(src + 4);
    CBf8[id] = pk8_fp8l(a, c);
  } else {  // ---- norms (f32 exact): one wave per code
    const int gw = (bb - 128) * 8 + (tid >> 6);
    const int l = tid & 63;
    const float4 a = *(const float4*)&CB[(size_t)gw * DIM + l * 8];
    const float4 b = *(const float4*)&CB[(size_t)gw * DIM + l * 8 + 4];
    float s = a.x * a.x + a.y * a.y + a.z * a.z + a.w * a.w +
              b.x * b.x + b.y * b.y + b.z * b.z + b.w * b.w;
#pragma unroll
    for (int m = 1; m < 64; m <<= 1) s += __shfl_xor(s, m, 64);
    if (l == 0) norms[gw] = s;
  }
}

// ------- main: barrier-free K-loop; af reg-pingpong from L2-hot CBf8; nt streaming -------
__global__ void __launch_bounds__(NT, 4)
vq_main15(const float* __restrict__ X, const long* __restrict__ CBf8,
          const float* __restrict__ CB, const float* __restrict__ norms,
          float* __restrict__ outq, double* __restrict__ lsum) {
  __shared__ long Xs[4096];           // 32 KB X fragment image (swizzled)
  __shared__ float snorm[KCODES];     // 4 KB
  __shared__ float redm[BM][4];
  __shared__ int redi[BM][4];
  __shared__ int idxs[BM];
  __shared__ float wpart[8];

  const int tid = threadIdx.x;
  const int lane = tid & 63;
  const int l15 = lane & 15;
  const int l4 = lane >> 4;
  const int wid = tid >> 6;
  const int wm = wid & 3;        // code group (64 codes)
  const int wn = wid >> 2;       // row group (32 rows)
  const int b = blockIdx.x;
  const int row0 = b * BM;

  for (int i = tid; i < KCODES; i += NT) snorm[i] = norms[i];

  // ---- prologue: nt-load one 2KB X row per wave-iter, cvt fp8, scatter to LDS ----
  float sq = 0.f;
#pragma unroll
  for (int c = 0; c < 8; ++c) {
    const int rl = c * 8 + wid;                        // local row 0..63
    const float* src = X + (size_t)(row0 + rl) * DIM + lane * 8;
    const fx4 a = __builtin_nontemporal_load((const fx4*)src);
    const fx4 d = __builtin_nontemporal_load((const fx4*)(src + 4));
    sq += a.x * a.x + a.y * a.y + a.z * a.z + a.w * a.w +
          d.x * d.x + d.y * d.y + d.z * d.z + d.w * d.w;
    const int q = lane;                                // quad index within row
    const int u = (q >> 3) * 512 + (rl >> 5) * 256 + ((rl >> 4) & 1) * 128 +
                  ((q >> 2) & 1) * 64 + (q & 3) * 16 + (rl & 15);
    Xs[xswz(u)] = pk8_fp8v(a, d);
  }
  __syncthreads();   // the ONLY barrier before the epilogue

  // ---- K-loop: no barriers; af prefetched 1 dk-phase ahead into reg ping-pong ----
  f32x4 acc[4][2];                 // [mf codes][nf rows]
  float rmin[2]; int ridx[2];
#pragma unroll
  for (int i = 0; i < 2; ++i) { rmin[i] = FLT_MAX; ridx[i] = 0; }

  const int bfrbase = wn * 256 + l4 * 16 + l15;   // runtime part of bfr unit index
  const long* cbw = CBf8 + wm * 512 + lane;       // per-wave af base

  long afA[2][4], afB[2][4];       // [ks][mf] ping-pong
#pragma unroll
  for (int ks = 0; ks < 2; ++ks)
#pragma unroll
    for (int mf = 0; mf < 4; ++mf)
      afA[ks][mf] = cbw[mf * 128 + ks * 64];   // t = 0

  for (int ct = 0; ct < NCT; ++ct) {
    const long* p = cbw + (size_t)ct * 8 * 2048;   // base for this ct (dk offsets immediate)
    {
      const f32x4 z = {0.f, 0.f, 0.f, 0.f};
#pragma unroll
      for (int mf = 0; mf < 4; ++mf)
#pragma unroll
        for (int nf = 0; nf < 2; ++nf) acc[mf][nf] = z;
    }
#pragma unroll
    for (int dk = 0; dk < NDK; ++dk) {
      // prefetch af for t+1 into the other buffer (one full MFMA phase ahead)
      if (ct * NDK + dk + 1 < TT) {
#pragma unroll
        for (int ks = 0; ks < 2; ++ks)
#pragma unroll
          for (int mf = 0; mf < 4; ++mf) {
            const long v = p[(dk + 1) * 2048 + mf * 128 + ks * 64];
            if (dk & 1) afA[ks][mf] = v; else afB[ks][mf] = v;
          }
      }
      // X fragments from LDS (swizzle folds to immediates; short latency)
      long bfr[2][2];  // [ks][nf]
#pragma unroll
      for (int ks = 0; ks < 2; ++ks)
#pragma unroll
        for (int nf = 0; nf < 2; ++nf) {
          const int u = bfrbase + dk * 512 + nf * 128 + ks * 64;
          bfr[ks][nf] = Xs[xswz(u)];
        }
#pragma unroll
      for (int ks = 0; ks < 2; ++ks)
#pragma unroll
        for (int mf = 0; mf < 4; ++mf)
#pragma unroll
          for (int nf = 0; nf < 2; ++nf)
            acc[mf][nf] = __builtin_amdgcn_mfma_f32_16x16x32_fp8_fp8(
                (dk & 1) ? afB[ks][mf] : afA[ks][mf], bfr[ks][nf],
                acc[mf][nf], 0, 0, 0);
    }
    // fold finished code-tile into running argmin
#pragma unroll
    for (int mf = 0; mf < 4; ++mf) {
#pragma unroll
      for (int r = 0; r < 4; ++r) {
        const int code = ct * BN + wm * 64 + mf * 16 + l4 * 4 + r;
        const float cn = snorm[code];
#pragma unroll
        for (int nf = 0; nf < 2; ++nf) {
          const float s = fmaf(-2.f, acc[mf][nf][r], cn);
          if (s < rmin[nf]) { rmin[nf] = s; ridx[nf] = code; }
        }
      }
    }
  }

  // cross-lane argmin (lanes l15, +16, +32, +48 share a row; tie -> lowest idx)
#pragma unroll
  for (int m = 16; m <= 32; m <<= 1) {
#pragma unroll
    for (int nf = 0; nf < 2; ++nf) {
      const float om = __shfl_xor(rmin[nf], m, 64);
      const int oi = __shfl_xor(ridx[nf], m, 64);
      if (om < rmin[nf] || (om == rmin[nf] && oi < ridx[nf])) {
        rmin[nf] = om; ridx[nf] = oi;
      }
    }
  }
  if (l4 == 0) {
#pragma unroll
    for (int nf = 0; nf < 2; ++nf) {
      const int row = wn * 32 + nf * 16 + l15;
      redm[row][wm] = rmin[nf];
      redi[row][wm] = ridx[nf];
    }
  }
  __syncthreads();

  float tot = sq;   // per-thread sum(x^2) from the prologue
  if (tid < BM) {   // cross-wave argmin reduce (4 code-group waves per row)
    float bm = redm[tid][0]; int bi = redi[tid][0];
#pragma unroll
    for (int c = 1; c < 4; ++c) {
      const float m_ = redm[tid][c]; const int i_ = redi[tid][c];
      if (m_ < bm || (m_ == bm && i_ < bi)) { bm = m_; bi = i_; }
    }
    idxs[tid] = bi;
    tot += bm;      // ||x-q||^2 = sum(x^2) + min(||c||^2 - 2 x.c)
  }
#pragma unroll
  for (int m = 1; m < 64; m <<= 1) tot += __shfl_xor(tot, m, 64);
  if (lane == 0) wpart[wid] = tot;
  __syncthreads();
  if (tid == 0) {
    double s = 0.0;
    for (int i = 0; i < 8; ++i) s += (double)wpart[i];
    atomicAdd(&lsum[b & 63], s);
  }

  // gather + write quantized (CB L2-hot read; nontemporal streaming store)
  for (int g = tid; g < BM * (DIM / 4); g += NT) {
    const int row = g >> 7;
    const int d4 = (g & 127) * 4;
    const int idx = idxs[row];
    const fx4 c4 = *(const fx4*)&CB[(size_t)idx * DIM + d4];
    __builtin_nontemporal_store(c4, (fx4*)&outq[(size_t)(row0 + row) * DIM + d4]);
  }
}

// ------------- fallback (round-2 path, tiny workspace; own constants) -------------
constexpr int FBM = 128, FBN = 256, FBK = 64, FNT = 512, FNDK = 8, FTT = 32;

__global__ void __launch_bounds__(FNT, 2)
vq_main_fb(const float* __restrict__ X, const float* __restrict__ CB,
           const float* __restrict__ norms, float* __restrict__ outq,
           double* __restrict__ lsum) {
  __shared__ u16 Xs[2][FBM * FBK];
  __shared__ u16 Cs[2][FBN * FBK];
  __shared__ float snorm[KCODES];
  __shared__ float redm[FBM][4];
  __shared__ int redi[FBM][4];
  __shared__ int idxs[FBM];
  __shared__ float wpart[8];

  const int tid = threadIdx.x;
  const int lane = tid & 63;
  const int l15 = lane & 15;
  const int l4 = lane >> 4;
  const int wid = tid >> 6;
  const int wm = wid & 3;
  const int wn = wid >> 2;
  const int row0 = blockIdx.x * FBM;

  for (int i = tid; i < KCODES; i += FNT) snorm[i] = norms[i];

  int xlds[2]; const float* xbase[2];
#pragma unroll
  for (int k = 0; k < 2; ++k) {
    const int u = tid + k * FNT;
    const int r = u >> 3, q = u & 7, ph = q ^ (r & 7);
    xlds[k] = r * FBK + ph * 8;
    xbase[k] = X + (size_t)(row0 + r) * DIM + q * 8;
  }
  int clds[4]; const float* cbase[4];
#pragma unroll
  for (int k = 0; k < 4; ++k) {
    const int u = tid + k * FNT;
    const int r = u >> 3, q = u & 7, ph = q ^ (r & 7);
    clds[k] = r * FBK + ph * 8;
    cbase[k] = CB + (size_t)r * DIM + q * 8;
  }

  f32x4 acc[4][4];
  float rmin[4]; int ridx[4];
#pragma unroll
  for (int i = 0; i < 4; ++i) { rmin[i] = FLT_MAX; ridx[i] = 0; }
  float sq = 0.f;

  float4 lx[2][2], lc[4][2];
  auto load_tile = [&](int tn) {
    const int ct = tn >> 3, dk = tn & 7;
    const int xo = dk * FBK;
    const size_t co = (size_t)ct * FBN * DIM + dk * FBK;
#pragma unroll
    for (int k = 0; k < 2; ++k) {
      lx[k][0] = *(const float4*)(xbase[k] + xo);
      lx[k][1] = *(const float4*)(xbase[k] + xo + 4);
    }
#pragma unroll
    for (int k = 0; k < 4; ++k) {
      lc[k][0] = *(const float4*)(cbase[k] + co);
      lc[k][1] = *(const float4*)(cbase[k] + co + 4);
    }
  };
  auto write_tile = [&](int bb, bool acc_sq) {
#pragma unroll
    for (int k = 0; k < 2; ++k) {
      u16x8 v;
      const float* f = (const float*)&lx[k][0];
#pragma unroll
      for (int j = 0; j < 8; ++j) {
        const float x = f[j];
        if (acc_sq) sq = fmaf(x, x, sq);
        v[j] = f2bf(x);
      }
      *(u16x8*)&Xs[bb][xlds[k]] = v;
    }
#pragma unroll
    for (int k = 0; k < 4; ++k) {
      u16x8 v;
      const float* f = (const float*)&lc[k][0];
#pragma unroll
      for (int j = 0; j < 8; ++j) v[j] = f2bf(f[j]);
      *(u16x8*)&Cs[bb][clds[k]] = v;
    }
  };

  load_tile(0);
  write_tile(0, true);
  __syncthreads();

  int cur = 0;
  for (int t = 0; t < FTT; ++t) {
    const int dk = t & 7;
    const bool pre = (t + 1 < FTT);
    if (pre) load_tile(t + 1);
    if (dk == 0) {
      const f32x4 z = {0.f, 0.f, 0.f, 0.f};
#pragma unroll
      for (int mf = 0; mf < 4; ++mf)
#pragma unroll
        for (int nf = 0; nf < 4; ++nf) acc[mf][nf] = z;
    }
    const u16* xb = Xs[cur];
    const u16* cb = Cs[cur];
#pragma unroll
    for (int ks = 0; ks < 2; ++ks) {
      bf16x8 af[4], bfr[4];
#pragma unroll
      for (int mf = 0; mf < 4; ++mf) {
        const int r = wm * 64 + mf * 16 + l15;
        const int ph = (ks * 4 + l4) ^ (r & 7);
        af[mf] = *(const bf16x8*)&cb[r * FBK + ph * 8];
      }
#pragma unroll
      for (int nf = 0; nf < 4; ++nf) {
        const int r = wn * 64 + nf * 16 + l15;
        const int ph = (ks * 4 + l4) ^ (r & 7);
        bfr[nf] = *(const bf16x8*)&xb[r * FBK + ph * 8];
      }
#pragma unroll
      for (int mf = 0; mf < 4; ++mf)
#pragma unroll
        for (int nf = 0; nf < 4; ++nf)
          acc[mf][nf] = __builtin_amdgcn_mfma_f32_16x16x32_bf16(
              af[mf], bfr[nf], acc[mf][nf], 0, 0, 0);
    }
    if (dk == FNDK - 1) {
      const int ct = t >> 3;
#pragma unroll
      for (int mf = 0; mf < 4; ++mf) {
#pragma unroll
        for (int r = 0; r < 4; ++r) {
          const int code = ct * FBN + wm * 64 + mf * 16 + l4 * 4 + r;
          const float cn = snorm[code];
#pragma unroll
          for (int nf = 0; nf < 4; ++nf) {
            const float s = fmaf(-2.f, acc[mf][nf][r], cn);
            if (s < rmin[nf]) { rmin[nf] = s; ridx[nf] = code; }
          }
        }
      }
    }
    if (pre) write_tile(cur ^ 1, (t + 1) < FNDK);
    __syncthreads();
    cur ^= 1;
  }

#pragma unroll
  for (int m = 16; m <= 32; m <<= 1) {
#pragma unroll
    for (int nf = 0; nf < 4; ++nf) {
      const float om = __shfl_xor(rmin[nf], m, 64);
      const int oi = __shfl_xor(ridx[nf], m, 64);
      if (om < rmin[nf] || (om == rmin[nf] && oi < ridx[nf])) {
        rmin[nf] = om; ridx[nf] = oi;
      }
    }
  }
  if (l4 == 0) {
#pragma unroll
    for (int nf = 0; nf < 4; ++nf) {
      const int row = wn * 64 + nf * 16 + l15;
      redm[row][wm] = rmin[nf];
      redi[row][wm] = ridx[nf];
    }
  }
  __syncthreads();

  float tot = sq;
  if (tid < FBM) {
    float bm = redm[tid][0]; int bi = redi[tid][0];
#pragma unroll
    for (int c = 1; c < 4; ++c) {
      const float m_ = redm[tid][c]; const int i_ = redi[tid][c];
      if (m_ < bm || (m_ == bm && i_ < bi)) { bm = m_; bi = i_; }
    }
    idxs[tid] = bi;
    tot += bm;
  }
#pragma unroll
  for (int m = 1; m < 64; m <<= 1) tot += __shfl_xor(tot, m, 64);
  if (lane == 0) wpart[wid] = tot;
  __syncthreads();
  if (tid == 0) {
    double s = 0.0;
    for (int i = 0; i < 8; ++i) s += (double)wpart[i];
    atomicAdd(&lsum[blockIdx.x & 63], s);
  }

  for (int g = tid; g < FBM * (DIM / 4); g += FNT) {
    const int row = g >> 7;
    const int d4 = (g & 127) * 4;
    const int idx = idxs[row];
    *(float4*)&outq[(size_t)(row0 + row) * DIM + d4] =
        *(const float4*)&CB[(size_t)idx * DIM + d4];
  }
}

__global__ void vq_norms_kernel(const float* __restrict__ cb,
                                float* __restrict__ norms) {
  const int gw = (int)((blockIdx.x * blockDim.x + threadIdx.x) >> 6);
  const int l = threadIdx.x & 63;
  const float4 a = *(const float4*)&cb[(size_t)gw * DIM + l * 8];
  const float4 b = *(const float4*)&cb[(size_t)gw * DIM + l * 8 + 4];
  float s = a.x * a.x + a.y * a.y + a.z * a.z + a.w * a.w +
            b.x * b.x + b.y * b.y + b.z * b.z + b.w * b.w;
#pragma unroll
  for (int m = 1; m < 64; m <<= 1) s += __shfl_xor(s, m, 64);
  if (l == 0) norms[gw] = s;
}

__global__ void vq_finalize_kernel(const double* __restrict__ lsum,
                                   float* __restrict__ out) {
  double t = 0.0;
  for (int i = 0; i < 64; ++i) t += lsum[i];
  out[0] = (float)(1.25 * t / (double)((size_t)LAT_ROWS * DIM));
}

extern "C" void kernel_launch(void* const* d_in, const int* in_sizes, int n_in,
                              void* d_out, int out_size, void* d_ws, size_t ws_size,
                              hipStream_t stream) {
  const float* X = (const float*)d_in[0];     // [32768, 512] f32
  const float* CB = (const float*)d_in[1];    // [1024, 512] f32
  float* out = (float*)d_out;                 // quantized [16777216] + loss [1]
  double* lsum = (double*)((char*)d_ws + WS_LSUM);   // 64 doubles
  float* norms = (float*)((char*)d_ws + WS_NORM);    // 1024 f32

  hipMemsetAsync(d_ws, 0, 512, stream);
  if (ws_size >= WS_NEEDED) {
    long* CBf8 = (long*)((char*)d_ws + WS_CBF8);
    vq_prep15<<<256, NT, 0, stream>>>(CB, CBf8, norms);
    vq_main15<<<LAT_ROWS / BM, NT, 0, stream>>>(X, CBf8, CB, norms, out, lsum);
  } else {
    vq_norms_kernel<<<KCODES / 4, 256, 0, stream>>>(CB, norms);
    vq_main_fb<<<LAT_ROWS / FBM, FNT, 0, stream>>>(X, CB, norms, out, lsum);
  }
  vq_finalize_kernel<<<1, 1, 0, stream>>>(lsum, out + (size_t)LAT_ROWS * DIM);
}

// Round 15
// 64.585 us; speedup vs baseline: 1.6494x; 1.6494x over previous
//
#include <hip/hip_runtime.h>
#include <cfloat>

#define LAT_ROWS 32768
#define DIM 512
#define KCODES 1024

constexpr int BM = 64;             // latent rows per block
constexpr int BN = 256;            // codes per ct-tile
constexpr int NT = 512;            // 8 waves: 4 code-groups x 2 row-groups
constexpr int NCT = 4;
constexpr int NDK = 8;
constexpr int TT = NCT * NDK;      // 32 single-dk phases
constexpr int CUNITS = BN * 64 / 8;   // 2048 8B-units per fp8 CB dk-tile (16 KB)

// workspace layout (bytes)
constexpr size_t WS_LSUM = 0;                      // 64 doubles
constexpr size_t WS_NORM = 512;                    // 1024 f32
constexpr size_t WS_CBF8 = 4608;                   // 512 KB fp8 (swizzled dk-tiles)
constexpr size_t WS_NEEDED = WS_CBF8 + 65536 * 8;  // ~530 KB

typedef float f32x4 __attribute__((ext_vector_type(4)));
typedef short bf16x8 __attribute__((ext_vector_type(8)));
typedef unsigned short u16;
typedef u16 u16x8 __attribute__((ext_vector_type(8)));

__device__ __forceinline__ u16 f2bf(float f) {  // RNE (fallback path)
  unsigned u = __float_as_uint(f);
  u += 0x7FFF + ((u >> 16) & 1);
  return (u16)(u >> 16);
}

// pack 8 f32 -> 8 fp8 e4m3 (RNE) as one 8-byte value
__device__ __forceinline__ long pk8_fp8l(const float4 a, const float4 c) {
  int lo = __builtin_amdgcn_cvt_pk_fp8_f32(a.x, a.y, 0, false);
  lo = __builtin_amdgcn_cvt_pk_fp8_f32(a.z, a.w, lo, true);
  int hi = __builtin_amdgcn_cvt_pk_fp8_f32(c.x, c.y, 0, false);
  hi = __builtin_amdgcn_cvt_pk_fp8_f32(c.z, c.w, hi, true);
  return ((long)(unsigned)hi << 32) | (unsigned)lo;
}

// LDS X-image swizzle: permute the l15 field by (4*l4 + 2*ks + (dk&1)).
// unit u = dk*512 + wn*256 + nf*128 + ks*64 + l4*16 + l15
__device__ __forceinline__ constexpr int xswz(int u) {
  const int add = ((u >> 2) & 12) + ((u >> 5) & 2) + ((u >> 9) & 1);
  return (u & ~15) | ((u + add) & 15);
}

#define GLOAD_LDS(g, l)                                     \
  __builtin_amdgcn_global_load_lds(                         \
      (const __attribute__((address_space(1))) void*)(g),   \
      (__attribute__((address_space(3))) void*)(l), 16, 0, 0)

// ------------- prep: CB -> fp8 swizzled dk-tiles + norms -------------
// CBf8 tile (ct,dk): phys slot (r, qp) holds logical quad q = (qp + 8 - ((r>>1)&7)) & 7
__global__ void __launch_bounds__(NT)
vq_prep16(const float* __restrict__ CB, long* __restrict__ CBf8,
          float* __restrict__ norms) {
  const int bb = blockIdx.x;
  const int tid = threadIdx.x;
  if (bb < 128) {  // ---- CB convert (65536 units)
    const int id = bb * NT + tid;
    const int ct = id >> 14;
    const int dk = (id >> 11) & 7;
    const int u = id & 2047;
    const int r = u >> 3, qp = u & 7;
    const int q = (qp + 8 - ((r >> 1) & 7)) & 7;
    const float* src = CB + ((size_t)ct * BN + r) * DIM + dk * 64 + q * 8;
    const float4 a = *(const float4*)src;
    const float4 c = *(const float4*)(src + 4);
    CBf8[id] = pk8_fp8l(a, c);
  } else {  // ---- norms (f32 exact): one wave per code
    const int gw = (bb - 128) * 8 + (tid >> 6);
    const int l = tid & 63;
    const float4 a = *(const float4*)&CB[(size_t)gw * DIM + l * 8];
    const float4 b = *(const float4*)&CB[(size_t)gw * DIM + l * 8 + 4];
    float s = a.x * a.x + a.y * a.y + a.z * a.z + a.w * a.w +
              b.x * b.x + b.y * b.y + b.z * b.z + b.w * b.w;
#pragma unroll
    for (int m = 1; m < 64; m <<= 1) s += __shfl_xor(s, m, 64);
    if (l == 0) norms[gw] = s;
  }
}

// ------- main: fused X prologue + dk-unrolled staged fp8 MFMA K-loop (plain mem ops) -------
__global__ void __launch_bounds__(NT, 4)
vq_main16(const float* __restrict__ X, const long* __restrict__ CBf8,
          const float* __restrict__ CB, const float* __restrict__ norms,
          float* __restrict__ outq, double* __restrict__ lsum) {
  __shared__ long Xs[4096];           // 32 KB X fragment image (swizzled)
  __shared__ long Cs[2][CUNITS];      // 16 KB x2 CB dk-tile dbuf
  __shared__ float snorm[KCODES];     // 4 KB
  __shared__ float redm[BM][4];
  __shared__ int redi[BM][4];
  __shared__ int idxs[BM];
  __shared__ float wpart[8];

  const int tid = threadIdx.x;
  const int lane = tid & 63;
  const int l15 = lane & 15;
  const int l4 = lane >> 4;
  const int wid = tid >> 6;
  const int wm = wid & 3;        // code group (64 codes)
  const int wn = wid >> 2;       // row group (32 rows)
  const int b = blockIdx.x;
  const int row0 = b * BM;

  auto stage = [&](int bf, int t) {   // 2 gload_lds (16B) -> 16 KB dk-tile
    const char* cp = (const char*)(CBf8 + (size_t)t * CUNITS);
    char* dst = (char*)&Cs[bf][0];
#pragma unroll
    for (int k = 0; k < 2; ++k) {
      const int o = (tid + k * NT) * 16;
      GLOAD_LDS(cp + o, dst + o);
    }
  };

  stage(0, 0);   // first tile's loads overlap the whole prologue

  for (int i = tid; i < KCODES; i += NT) snorm[i] = norms[i];

  // ---- prologue: wave reads one 2KB row/iter (coalesced), cvt fp8, scatter to LDS ----
  float sq = 0.f;
#pragma unroll
  for (int c = 0; c < 8; ++c) {
    const int rl = c * 8 + wid;                        // local row 0..63
    const float* src = X + (size_t)(row0 + rl) * DIM + lane * 8;
    const float4 a = *(const float4*)src;
    const float4 d = *(const float4*)(src + 4);
    sq += a.x * a.x + a.y * a.y + a.z * a.z + a.w * a.w +
          d.x * d.x + d.y * d.y + d.z * d.z + d.w * d.w;
    const int q = lane;                                // quad index within row
    const int u = (q >> 3) * 512 + (rl >> 5) * 256 + ((rl >> 4) & 1) * 128 +
                  ((q >> 2) & 1) * 64 + (q & 3) * 16 + (rl & 15);
    Xs[xswz(u)] = pk8_fp8l(a, d);
  }
  __syncthreads();   // publishes Xs + snorm + tile 0 (vmcnt drained)

  // ---- K-loop: runtime ct, unrolled dk -> addresses/predicates fold, no spill ----
  f32x4 acc[4][2];                 // [mf codes][nf rows]
  float rmin[2]; int ridx[2];
#pragma unroll
  for (int i = 0; i < 2; ++i) { rmin[i] = FLT_MAX; ridx[i] = 0; }

  const int bfrbase = wn * 256 + l4 * 16 + l15;   // runtime part of bfr unit index
  const int afrow = (wm * 64 + l15) * 8;          // runtime part of af slot

  for (int ct = 0; ct < NCT; ++ct) {
    {
      const f32x4 z = {0.f, 0.f, 0.f, 0.f};
#pragma unroll
      for (int mf = 0; mf < 4; ++mf)
#pragma unroll
        for (int nf = 0; nf < 2; ++nf) acc[mf][nf] = z;
    }
#pragma unroll
    for (int dk = 0; dk < NDK; ++dk) {
      const int t = ct * NDK + dk;
      const int cur = dk & 1;      // ct*8 even -> compile-time
      if (t + 1 < TT) stage(cur ^ 1, t + 1);   // prefetch spans this MFMA phase

      // X fragments from the block-resident LDS image (swizzle folds to immediate)
      long bfr[2][2];  // [ks][nf]
#pragma unroll
      for (int ks = 0; ks < 2; ++ks)
#pragma unroll
        for (int nf = 0; nf < 2; ++nf) {
          const int u = bfrbase + dk * 512 + nf * 128 + ks * 64;
          bfr[ks][nf] = Xs[xswz(u)];
        }
#pragma unroll
      for (int ks = 0; ks < 2; ++ks) {
        long af[4];
#pragma unroll
        for (int mf = 0; mf < 4; ++mf) {
          const int ph = ((ks * 4 + l4) + (l15 >> 1)) & 7;  // additive swizzle
          af[mf] = Cs[cur][afrow + mf * 128 + ph];
        }
#pragma unroll
        for (int mf = 0; mf < 4; ++mf)
#pragma unroll
          for (int nf = 0; nf < 2; ++nf)
            acc[mf][nf] = __builtin_amdgcn_mfma_f32_16x16x32_fp8_fp8(
                af[mf], bfr[ks][nf], acc[mf][nf], 0, 0, 0);
      }
      __syncthreads();   // buffer swap; co-resident block hides the drain
    }
    // fold finished code-tile into running argmin (runtime ct is fine here)
#pragma unroll
    for (int mf = 0; mf < 4; ++mf) {
#pragma unroll
      for (int r = 0; r < 4; ++r) {
        const int code = ct * BN + wm * 64 + mf * 16 + l4 * 4 + r;
        const float cn = snorm[code];
#pragma unroll
        for (int nf = 0; nf < 2; ++nf) {
          const float s = fmaf(-2.f, acc[mf][nf][r], cn);
          if (s < rmin[nf]) { rmin[nf] = s; ridx[nf] = code; }
        }
      }
    }
  }

  // cross-lane argmin (lanes l15, +16, +32, +48 share a row; tie -> lowest idx)
#pragma unroll
  for (int m = 16; m <= 32; m <<= 1) {
#pragma unroll
    for (int nf = 0; nf < 2; ++nf) {
      const float om = __shfl_xor(rmin[nf], m, 64);
      const int oi = __shfl_xor(ridx[nf], m, 64);
      if (om < rmin[nf] || (om == rmin[nf] && oi < ridx[nf])) {
        rmin[nf] = om; ridx[nf] = oi;
      }
    }
  }
  if (l4 == 0) {
#pragma unroll
    for (int nf = 0; nf < 2; ++nf) {
      const int row = wn * 32 + nf * 16 + l15;
      redm[row][wm] = rmin[nf];
      redi[row][wm] = ridx[nf];
    }
  }
  __syncthreads();

  float tot = sq;   // per-thread sum(x^2) from the prologue
  if (tid < BM) {   // cross-wave argmin reduce (4 code-group waves per row)
    float bm = redm[tid][0]; int bi = redi[tid][0];
#pragma unroll
    for (int c = 1; c < 4; ++c) {
      const float m_ = redm[tid][c]; const int i_ = redi[tid][c];
      if (m_ < bm || (m_ == bm && i_ < bi)) { bm = m_; bi = i_; }
    }
    idxs[tid] = bi;
    tot += bm;      // ||x-q||^2 = sum(x^2) + min(||c||^2 - 2 x.c)
  }
#pragma unroll
  for (int m = 1; m < 64; m <<= 1) tot += __shfl_xor(tot, m, 64);
  if (lane == 0) wpart[wid] = tot;
  __syncthreads();
  if (tid == 0) {
    double s = 0.0;
    for (int i = 0; i < 8; ++i) s += (double)wpart[i];
    atomicAdd(&lsum[b & 63], s);
  }

  // gather + write quantized (exact f32 codebook rows, CB is L2-hot)
  for (int g = tid; g < BM * (DIM / 4); g += NT) {
    const int row = g >> 7;
    const int d4 = (g & 127) * 4;
    const int idx = idxs[row];
    *(float4*)&outq[(size_t)(row0 + row) * DIM + d4] =
        *(const float4*)&CB[(size_t)idx * DIM + d4];
  }
}

// ------------- fallback (round-2 path, tiny workspace; own constants) -------------
constexpr int FBM = 128, FBN = 256, FBK = 64, FNT = 512, FNDK = 8, FTT = 32;

__global__ void __launch_bounds__(FNT, 2)
vq_main_fb(const float* __restrict__ X, const float* __restrict__ CB,
           const float* __restrict__ norms, float* __restrict__ outq,
           double* __restrict__ lsum) {
  __shared__ u16 Xs[2][FBM * FBK];
  __shared__ u16 Cs[2][FBN * FBK];
  __shared__ float snorm[KCODES];
  __shared__ float redm[FBM][4];
  __shared__ int redi[FBM][4];
  __shared__ int idxs[FBM];
  __shared__ float wpart[8];

  const int tid = threadIdx.x;
  const int lane = tid & 63;
  const int l15 = lane & 15;
  const int l4 = lane >> 4;
  const int wid = tid >> 6;
  const int wm = wid & 3;
  const int wn = wid >> 2;
  const int row0 = blockIdx.x * FBM;

  for (int i = tid; i < KCODES; i += FNT) snorm[i] = norms[i];

  int xlds[2]; const float* xbase[2];
#pragma unroll
  for (int k = 0; k < 2; ++k) {
    const int u = tid + k * FNT;
    const int r = u >> 3, q = u & 7, ph = q ^ (r & 7);
    xlds[k] = r * FBK + ph * 8;
    xbase[k] = X + (size_t)(row0 + r) * DIM + q * 8;
  }
  int clds[4]; const float* cbase[4];
#pragma unroll
  for (int k = 0; k < 4; ++k) {
    const int u = tid + k * FNT;
    const int r = u >> 3, q = u & 7, ph = q ^ (r & 7);
    clds[k] = r * FBK + ph * 8;
    cbase[k] = CB + (size_t)r * DIM + q * 8;
  }

  f32x4 acc[4][4];
  float rmin[4]; int ridx[4];
#pragma unroll
  for (int i = 0; i < 4; ++i) { rmin[i] = FLT_MAX; ridx[i] = 0; }
  float sq = 0.f;

  float4 lx[2][2], lc[4][2];
  auto load_tile = [&](int tn) {
    const int ct = tn >> 3, dk = tn & 7;
    const int xo = dk * FBK;
    const size_t co = (size_t)ct * FBN * DIM + dk * FBK;
#pragma unroll
    for (int k = 0; k < 2; ++k) {
      lx[k][0] = *(const float4*)(xbase[k] + xo);
      lx[k][1] = *(const float4*)(xbase[k] + xo + 4);
    }
#pragma unroll
    for (int k = 0; k < 4; ++k) {
      lc[k][0] = *(const float4*)(cbase[k] + co);
      lc[k][1] = *(const float4*)(cbase[k] + co + 4);
    }
  };
  auto write_tile = [&](int bb, bool acc_sq) {
#pragma unroll
    for (int k = 0; k < 2; ++k) {
      u16x8 v;
      const float* f = (const float*)&lx[k][0];
#pragma unroll
      for (int j = 0; j < 8; ++j) {
        const float x = f[j];
        if (acc_sq) sq = fmaf(x, x, sq);
        v[j] = f2bf(x);
      }
      *(u16x8*)&Xs[bb][xlds[k]] = v;
    }
#pragma unroll
    for (int k = 0; k < 4; ++k) {
      u16x8 v;
      const float* f = (const float*)&lc[k][0];
#pragma unroll
      for (int j = 0; j < 8; ++j) v[j] = f2bf(f[j]);
      *(u16x8*)&Cs[bb][clds[k]] = v;
    }
  };

  load_tile(0);
  write_tile(0, true);
  __syncthreads();

  int cur = 0;
  for (int t = 0; t < FTT; ++t) {
    const int dk = t & 7;
    const bool pre = (t + 1 < FTT);
    if (pre) load_tile(t + 1);
    if (dk == 0) {
      const f32x4 z = {0.f, 0.f, 0.f, 0.f};
#pragma unroll
      for (int mf = 0; mf < 4; ++mf)
#pragma unroll
        for (int nf = 0; nf < 4; ++nf) acc[mf][nf] = z;
    }
    const u16* xb = Xs[cur];
    const u16* cb = Cs[cur];
#pragma unroll
    for (int ks = 0; ks < 2; ++ks) {
      bf16x8 af[4], bfr[4];
#pragma unroll
      for (int mf = 0; mf < 4; ++mf) {
        const int r = wm * 64 + mf * 16 + l15;
        const int ph = (ks * 4 + l4) ^ (r & 7);
        af[mf] = *(const bf16x8*)&cb[r * FBK + ph * 8];
      }
#pragma unroll
      for (int nf = 0; nf < 4; ++nf) {
        const int r = wn * 64 + nf * 16 + l15;
        const int ph = (ks * 4 + l4) ^ (r & 7);
        bfr[nf] = *(const bf16x8*)&xb[r * FBK + ph * 8];
      }
#pragma unroll
      for (int mf = 0; mf < 4; ++mf)
#pragma unroll
        for (int nf = 0; nf < 4; ++nf)
          acc[mf][nf] = __builtin_amdgcn_mfma_f32_16x16x32_bf16(
              af[mf], bfr[nf], acc[mf][nf], 0, 0, 0);
    }
    if (dk == FNDK - 1) {
      const int ct = t >> 3;
#pragma unroll
      for (int mf = 0; mf < 4; ++mf) {
#pragma unroll
        for (int r = 0; r < 4; ++r) {
          const int code = ct * FBN + wm * 64 + mf * 16 + l4 * 4 + r;
          const float cn = snorm[code];
#pragma unroll
          for (int nf = 0; nf < 4; ++nf) {
            const float s = fmaf(-2.f, acc[mf][nf][r], cn);
            if (s < rmin[nf]) { rmin[nf] = s; ridx[nf] = code; }
          }
        }
      }
    }
    if (pre) write_tile(cur ^ 1, (t + 1) < FNDK);
    __syncthreads();
    cur ^= 1;
  }

#pragma unroll
  for (int m = 16; m <= 32; m <<= 1) {
#pragma unroll
    for (int nf = 0; nf < 4; ++nf) {
      const float om = __shfl_xor(rmin[nf], m, 64);
      const int oi = __shfl_xor(ridx[nf], m, 64);
      if (om < rmin[nf] || (om == rmin[nf] && oi < ridx[nf])) {
        rmin[nf] = om; ridx[nf] = oi;
      }
    }
  }
  if (l4 == 0) {
#pragma unroll
    for (int nf = 0; nf < 4; ++nf) {
      const int row = wn * 64 + nf * 16 + l15;
      redm[row][wm] = rmin[nf];
      redi[row][wm] = ridx[nf];
    }
  }
  __syncthreads();

  float tot = sq;
  if (tid < FBM) {
    float bm = redm[tid][0]; int bi = redi[tid][0];
#pragma unroll
    for (int c = 1; c < 4; ++c) {
      const float m_ = redm[tid][c]; const int i_ = redi[tid][c];
      if (m_ < bm || (m_ == bm && i_ < bi)) { bm = m_; bi = i_; }
    }
    idxs[tid] = bi;
    tot += bm;
  }
#pragma unroll
  for (int m = 1; m < 64; m <<= 1) tot += __shfl_xor(tot, m, 64);
  if (lane == 0) wpart[wid] = tot;
  __syncthreads();
  if (tid == 0) {
    double s = 0.0;
    for (int i = 0; i < 8; ++i) s += (double)wpart[i];
    atomicAdd(&lsum[blockIdx.x & 63], s);
  }

  for (int g = tid; g < FBM * (DIM / 4); g += FNT) {
    const int row = g >> 7;
    const int d4 = (g & 127) * 4;
    const int idx = idxs[row];
    *(float4*)&outq[(size_t)(row0 + row) * DIM + d4] =
        *(const float4*)&CB[(size_t)idx * DIM + d4];
  }
}

__global__ void vq_norms_kernel(const float* __restrict__ cb,
                                float* __restrict__ norms) {
  const int gw = (int)((blockIdx.x * blockDim.x + threadIdx.x) >> 6);
  const int l = threadIdx.x & 63;
  const float4 a = *(const float4*)&cb[(size_t)gw * DIM + l * 8];
  const float4 b = *(const float4*)&cb[(size_t)gw * DIM + l * 8 + 4];
  float s = a.x * a.x + a.y * a.y + a.z * a.z + a.w * a.w +
            b.x * b.x + b.y * b.y + b.z * b.z + b.w * b.w;
#pragma unroll
  for (int m = 1; m < 64; m <<= 1) s += __shfl_xor(s, m, 64);
  if (l == 0) norms[gw] = s;
}

__global__ void vq_finalize_kernel(const double* __restrict__ lsum,
                                   float* __restrict__ out) {
  double t = 0.0;
  for (int i = 0; i < 64; ++i) t += lsum[i];
  out[0] = (float)(1.25 * t / (double)((size_t)LAT_ROWS * DIM));
}

extern "C" void kernel_launch(void* const* d_in, const int* in_sizes, int n_in,
                              void* d_out, int out_size, void* d_ws, size_t ws_size,
                              hipStream_t stream) {
  const float* X = (const float*)d_in[0];     // [32768, 512] f32
  const float* CB = (const float*)d_in[1];    // [1024, 512] f32
  float* out = (float*)d_out;                 // quantized [16777216] + loss [1]
  double* lsum = (double*)((char*)d_ws + WS_LSUM);   // 64 doubles
  float* norms = (float*)((char*)d_ws + WS_NORM);    // 1024 f32

  hipMemsetAsync(d_ws, 0, 512, stream);
  if (ws_size >= WS_NEEDED) {
    long* CBf8 = (long*)((char*)d_ws + WS_CBF8);
    vq_prep16<<<256, NT, 0, stream>>>(CB, CBf8, norms);
    vq_main16<<<LAT_ROWS / BM, NT, 0, stream>>>(X, CBf8, CB, norms, out, lsum);
  } else {
    vq_norms_kernel<<<KCODES / 4, 256, 0, stream>>>(CB, norms);
    vq_main_fb<<<LAT_ROWS / FBM, FNT, 0, stream>>>(X, CB, norms, out, lsum);
  }
  vq_finalize_kernel<<<1, 1, 0, stream>>>(lsum, out + (size_t)LAT_ROWS * DIM);
}

// Round 16
// 60.492 us; speedup vs baseline: 1.7610x; 1.0677x over previous
//
#include <hip/hip_runtime.h>
#include <cfloat>

#define LAT_ROWS 32768
#define DIM 512
#define KCODES 1024

constexpr int BM = 64;             // latent rows per block
constexpr int BN = 256;            // codes per ct-tile
constexpr int NT = 512;            // 8 waves: 4 code-groups x 2 row-groups
constexpr int NCT = 4;
constexpr int NDK = 8;
constexpr int TT = NCT * NDK;      // 32 single-dk phases
constexpr int CUNITS = BN * 64 / 8;   // 2048 8B-units per fp8 CB dk-tile (16 KB)

// workspace layout (bytes)
constexpr size_t WS_LSUM = 0;                      // 64 doubles
constexpr size_t WS_NORM = 512;                    // 1024 f32
constexpr size_t WS_CBF8 = 4608;                   // 512 KB fp8 (swizzled dk-tiles)
constexpr size_t WS_NEEDED = WS_CBF8 + 65536 * 8;  // ~530 KB

typedef float f32x4 __attribute__((ext_vector_type(4)));
typedef short bf16x8 __attribute__((ext_vector_type(8)));
typedef unsigned short u16;
typedef u16 u16x8 __attribute__((ext_vector_type(8)));

__device__ __forceinline__ u16 f2bf(float f) {  // RNE (fallback path)
  unsigned u = __float_as_uint(f);
  u += 0x7FFF + ((u >> 16) & 1);
  return (u16)(u >> 16);
}

// pack 8 f32 -> 8 fp8 e4m3 (RNE) as one 8-byte value
__device__ __forceinline__ long pk8_fp8l(const float4 a, const float4 c) {
  int lo = __builtin_amdgcn_cvt_pk_fp8_f32(a.x, a.y, 0, false);
  lo = __builtin_amdgcn_cvt_pk_fp8_f32(a.z, a.w, lo, true);
  int hi = __builtin_amdgcn_cvt_pk_fp8_f32(c.x, c.y, 0, false);
  hi = __builtin_amdgcn_cvt_pk_fp8_f32(c.z, c.w, hi, true);
  return ((long)(unsigned)hi << 32) | (unsigned)lo;
}

// LDS X-image swizzle: permute the l15 field by (4*l4 + 2*ks + (dk&1)).
// unit u = dk*512 + wn*256 + nf*128 + ks*64 + l4*16 + l15
__device__ __forceinline__ constexpr int xswz(int u) {
  const int add = ((u >> 2) & 12) + ((u >> 5) & 2) + ((u >> 9) & 1);
  return (u & ~15) | ((u + add) & 15);
}

#define GLOAD_LDS(g, l)                                     \
  __builtin_amdgcn_global_load_lds(                         \
      (const __attribute__((address_space(1))) void*)(g),   \
      (__attribute__((address_space(3))) void*)(l), 16, 0, 0)

// ------------- prep: CB -> fp8 swizzled dk-tiles + norms -------------
// CBf8 tile (ct,dk): phys slot (r, qp) holds logical quad q = (qp + 8 - ((r>>1)&7)) & 7
__global__ void __launch_bounds__(NT)
vq_prep17(const float* __restrict__ CB, long* __restrict__ CBf8,
          float* __restrict__ norms) {
  const int bb = blockIdx.x;
  const int tid = threadIdx.x;
  if (bb < 128) {  // ---- CB convert (65536 units)
    const int id = bb * NT + tid;
    const int ct = id >> 14;
    const int dk = (id >> 11) & 7;
    const int u = id & 2047;
    const int r = u >> 3, qp = u & 7;
    const int q = (qp + 8 - ((r >> 1) & 7)) & 7;
    const float* src = CB + ((size_t)ct * BN + r) * DIM + dk * 64 + q * 8;
    const float4 a = *(const float4*)src;
    const float4 c = *(const float4*)(src + 4);
    CBf8[id] = pk8_fp8l(a, c);
  } else {  // ---- norms (f32 exact): one wave per code
    const int gw = (bb - 128) * 8 + (tid >> 6);
    const int l = tid & 63;
    const float4 a = *(const float4*)&CB[(size_t)gw * DIM + l * 8];
    const float4 b = *(const float4*)&CB[(size_t)gw * DIM + l * 8 + 4];
    float s = a.x * a.x + a.y * a.y + a.z * a.z + a.w * a.w +
              b.x * b.x + b.y * b.y + b.z * b.z + b.w * b.w;
#pragma unroll
    for (int m = 1; m < 64; m <<= 1) s += __shfl_xor(s, m, 64);
    if (l == 0) norms[gw] = s;
  }
}

// ------- main: fused X prologue + dk-unrolled staged fp8 MFMA K-loop + T5 setprio -------
__global__ void __launch_bounds__(NT, 4)
vq_main17(const float* __restrict__ X, const long* __restrict__ CBf8,
          const float* __restrict__ CB, const float* __restrict__ norms,
          float* __restrict__ outq, double* __restrict__ lsum) {
  __shared__ long Xs[4096];           // 32 KB X fragment image (swizzled)
  __shared__ long Cs[2][CUNITS];      // 16 KB x2 CB dk-tile dbuf
  __shared__ float snorm[KCODES];     // 4 KB
  __shared__ float redm[BM][4];
  __shared__ int redi[BM][4];
  __shared__ int idxs[BM];
  __shared__ float wpart[8];

  const int tid = threadIdx.x;
  const int lane = tid & 63;
  const int l15 = lane & 15;
  const int l4 = lane >> 4;
  const int wid = tid >> 6;
  const int wm = wid & 3;        // code group (64 codes)
  const int wn = wid >> 2;       // row group (32 rows)
  const int b = blockIdx.x;
  const int row0 = b * BM;

  auto stage = [&](int bf, int t) {   // 2 gload_lds (16B) -> 16 KB dk-tile
    const char* cp = (const char*)(CBf8 + (size_t)t * CUNITS);
    char* dst = (char*)&Cs[bf][0];
#pragma unroll
    for (int k = 0; k < 2; ++k) {
      const int o = (tid + k * NT) * 16;
      GLOAD_LDS(cp + o, dst + o);
    }
  };

  stage(0, 0);   // first tile's loads overlap the whole prologue

  for (int i = tid; i < KCODES; i += NT) snorm[i] = norms[i];

  // ---- prologue: wave reads one 2KB row/iter (coalesced), cvt fp8, scatter to LDS ----
  float sq = 0.f;
#pragma unroll
  for (int c = 0; c < 8; ++c) {
    const int rl = c * 8 + wid;                        // local row 0..63
    const float* src = X + (size_t)(row0 + rl) * DIM + lane * 8;
    const float4 a = *(const float4*)src;
    const float4 d = *(const float4*)(src + 4);
    sq += a.x * a.x + a.y * a.y + a.z * a.z + a.w * a.w +
          d.x * d.x + d.y * d.y + d.z * d.z + d.w * d.w;
    const int q = lane;                                // quad index within row
    const int u = (q >> 3) * 512 + (rl >> 5) * 256 + ((rl >> 4) & 1) * 128 +
                  ((q >> 2) & 1) * 64 + (q & 3) * 16 + (rl & 15);
    Xs[xswz(u)] = pk8_fp8l(a, d);
  }
  __syncthreads();   // publishes Xs + snorm + tile 0 (vmcnt drained)

  // ---- K-loop: runtime ct, unrolled dk; setprio(1) around MFMA cluster (T5) ----
  f32x4 acc[4][2];                 // [mf codes][nf rows]
  float rmin[2]; int ridx[2];
#pragma unroll
  for (int i = 0; i < 2; ++i) { rmin[i] = FLT_MAX; ridx[i] = 0; }

  const int bfrbase = wn * 256 + l4 * 16 + l15;   // runtime part of bfr unit index
  const int afrow = (wm * 64 + l15) * 8;          // runtime part of af slot

  for (int ct = 0; ct < NCT; ++ct) {
    {
      const f32x4 z = {0.f, 0.f, 0.f, 0.f};
#pragma unroll
      for (int mf = 0; mf < 4; ++mf)
#pragma unroll
        for (int nf = 0; nf < 2; ++nf) acc[mf][nf] = z;
    }
#pragma unroll
    for (int dk = 0; dk < NDK; ++dk) {
      const int t = ct * NDK + dk;
      const int cur = dk & 1;      // ct*8 even -> compile-time
      if (t + 1 < TT) stage(cur ^ 1, t + 1);   // prefetch spans this MFMA phase

      // X fragments from the block-resident LDS image (swizzle folds to immediate)
      long bfr[2][2];  // [ks][nf]
#pragma unroll
      for (int ks = 0; ks < 2; ++ks)
#pragma unroll
        for (int nf = 0; nf < 2; ++nf) {
          const int u = bfrbase + dk * 512 + nf * 128 + ks * 64;
          bfr[ks][nf] = Xs[xswz(u)];
        }
#pragma unroll
      for (int ks = 0; ks < 2; ++ks) {
        long af[4];
#pragma unroll
        for (int mf = 0; mf < 4; ++mf) {
          const int ph = ((ks * 4 + l4) + (l15 >> 1)) & 7;  // additive swizzle
          af[mf] = Cs[cur][afrow + mf * 128 + ph];
        }
        __builtin_amdgcn_s_setprio(1);
#pragma unroll
        for (int mf = 0; mf < 4; ++mf)
#pragma unroll
          for (int nf = 0; nf < 2; ++nf)
            acc[mf][nf] = __builtin_amdgcn_mfma_f32_16x16x32_fp8_fp8(
                af[mf], bfr[ks][nf], acc[mf][nf], 0, 0, 0);
        __builtin_amdgcn_s_setprio(0);
      }
      __syncthreads();   // buffer swap; co-resident block hides the drain
    }
    // fold finished code-tile into running argmin (runtime ct is fine here)
#pragma unroll
    for (int mf = 0; mf < 4; ++mf) {
#pragma unroll
      for (int r = 0; r < 4; ++r) {
        const int code = ct * BN + wm * 64 + mf * 16 + l4 * 4 + r;
        const float cn = snorm[code];
#pragma unroll
        for (int nf = 0; nf < 2; ++nf) {
          const float s = fmaf(-2.f, acc[mf][nf][r], cn);
          if (s < rmin[nf]) { rmin[nf] = s; ridx[nf] = code; }
        }
      }
    }
  }

  // cross-lane argmin (lanes l15, +16, +32, +48 share a row; tie -> lowest idx)
#pragma unroll
  for (int m = 16; m <= 32; m <<= 1) {
#pragma unroll
    for (int nf = 0; nf < 2; ++nf) {
      const float om = __shfl_xor(rmin[nf], m, 64);
      const int oi = __shfl_xor(ridx[nf], m, 64);
      if (om < rmin[nf] || (om == rmin[nf] && oi < ridx[nf])) {
        rmin[nf] = om; ridx[nf] = oi;
      }
    }
  }
  if (l4 == 0) {
#pragma unroll
    for (int nf = 0; nf < 2; ++nf) {
      const int row = wn * 32 + nf * 16 + l15;
      redm[row][wm] = rmin[nf];
      redi[row][wm] = ridx[nf];
    }
  }
  __syncthreads();

  float tot = sq;   // per-thread sum(x^2) from the prologue
  if (tid < BM) {   // cross-wave argmin reduce (4 code-group waves per row)
    float bm = redm[tid][0]; int bi = redi[tid][0];
#pragma unroll
    for (int c = 1; c < 4; ++c) {
      const float m_ = redm[tid][c]; const int i_ = redi[tid][c];
      if (m_ < bm || (m_ == bm && i_ < bi)) { bm = m_; bi = i_; }
    }
    idxs[tid] = bi;
    tot += bm;      // ||x-q||^2 = sum(x^2) + min(||c||^2 - 2 x.c)
  }
#pragma unroll
  for (int m = 1; m < 64; m <<= 1) tot += __shfl_xor(tot, m, 64);
  if (lane == 0) wpart[wid] = tot;
  __syncthreads();
  if (tid == 0) {
    double s = 0.0;
    for (int i = 0; i < 8; ++i) s += (double)wpart[i];
    atomicAdd(&lsum[b & 63], s);
  }

  // gather + write quantized (exact f32 codebook rows, CB is L2-hot)
  for (int g = tid; g < BM * (DIM / 4); g += NT) {
    const int row = g >> 7;
    const int d4 = (g & 127) * 4;
    const int idx = idxs[row];
    *(float4*)&outq[(size_t)(row0 + row) * DIM + d4] =
        *(const float4*)&CB[(size_t)idx * DIM + d4];
  }
}

// ------------- fallback (round-2 path, tiny workspace; own constants) -------------
constexpr int FBM = 128, FBN = 256, FBK = 64, FNT = 512, FNDK = 8, FTT = 32;

__global__ void __launch_bounds__(FNT, 2)
vq_main_fb(const float* __restrict__ X, const float* __restrict__ CB,
           const float* __restrict__ norms, float* __restrict__ outq,
           double* __restrict__ lsum) {
  __shared__ u16 Xs[2][FBM * FBK];
  __shared__ u16 Cs[2][FBN * FBK];
  __shared__ float snorm[KCODES];
  __shared__ float redm[FBM][4];
  __shared__ int redi[FBM][4];
  __shared__ int idxs[FBM];
  __shared__ float wpart[8];

  const int tid = threadIdx.x;
  const int lane = tid & 63;
  const int l15 = lane & 15;
  const int l4 = lane >> 4;
  const int wid = tid >> 6;
  const int wm = wid & 3;
  const int wn = wid >> 2;
  const int row0 = blockIdx.x * FBM;

  for (int i = tid; i < KCODES; i += FNT) snorm[i] = norms[i];

  int xlds[2]; const float* xbase[2];
#pragma unroll
  for (int k = 0; k < 2; ++k) {
    const int u = tid + k * FNT;
    const int r = u >> 3, q = u & 7, ph = q ^ (r & 7);
    xlds[k] = r * FBK + ph * 8;
    xbase[k] = X + (size_t)(row0 + r) * DIM + q * 8;
  }
  int clds[4]; const float* cbase[4];
#pragma unroll
  for (int k = 0; k < 4; ++k) {
    const int u = tid + k * FNT;
    const int r = u >> 3, q = u & 7, ph = q ^ (r & 7);
    clds[k] = r * FBK + ph * 8;
    cbase[k] = CB + (size_t)r * DIM + q * 8;
  }

  f32x4 acc[4][4];
  float rmin[4]; int ridx[4];
#pragma unroll
  for (int i = 0; i < 4; ++i) { rmin[i] = FLT_MAX; ridx[i] = 0; }
  float sq = 0.f;

  float4 lx[2][2], lc[4][2];
  auto load_tile = [&](int tn) {
    const int ct = tn >> 3, dk = tn & 7;
    const int xo = dk * FBK;
    const size_t co = (size_t)ct * FBN * DIM + dk * FBK;
#pragma unroll
    for (int k = 0; k < 2; ++k) {
      lx[k][0] = *(const float4*)(xbase[k] + xo);
      lx[k][1] = *(const float4*)(xbase[k] + xo + 4);
    }
#pragma unroll
    for (int k = 0; k < 4; ++k) {
      lc[k][0] = *(const float4*)(cbase[k] + co);
      lc[k][1] = *(const float4*)(cbase[k] + co + 4);
    }
  };
  auto write_tile = [&](int bb, bool acc_sq) {
#pragma unroll
    for (int k = 0; k < 2; ++k) {
      u16x8 v;
      const float* f = (const float*)&lx[k][0];
#pragma unroll
      for (int j = 0; j < 8; ++j) {
        const float x = f[j];
        if (acc_sq) sq = fmaf(x, x, sq);
        v[j] = f2bf(x);
      }
      *(u16x8*)&Xs[bb][xlds[k]] = v;
    }
#pragma unroll
    for (int k = 0; k < 4; ++k) {
      u16x8 v;
      const float* f = (const float*)&lc[k][0];
#pragma unroll
      for (int j = 0; j < 8; ++j) v[j] = f2bf(f[j]);
      *(u16x8*)&Cs[bb][clds[k]] = v;
    }
  };

  load_tile(0);
  write_tile(0, true);
  __syncthreads();

  int cur = 0;
  for (int t = 0; t < FTT; ++t) {
    const int dk = t & 7;
    const bool pre = (t + 1 < FTT);
    if (pre) load_tile(t + 1);
    if (dk == 0) {
      const f32x4 z = {0.f, 0.f, 0.f, 0.f};
#pragma unroll
      for (int mf = 0; mf < 4; ++mf)
#pragma unroll
        for (int nf = 0; nf < 4; ++nf) acc[mf][nf] = z;
    }
    const u16* xb = Xs[cur];
    const u16* cb = Cs[cur];
#pragma unroll
    for (int ks = 0; ks < 2; ++ks) {
      bf16x8 af[4], bfr[4];
#pragma unroll
      for (int mf = 0; mf < 4; ++mf) {
        const int r = wm * 64 + mf * 16 + l15;
        const int ph = (ks * 4 + l4) ^ (r & 7);
        af[mf] = *(const bf16x8*)&cb[r * FBK + ph * 8];
      }
#pragma unroll
      for (int nf = 0; nf < 4; ++nf) {
        const int r = wn * 64 + nf * 16 + l15;
        const int ph = (ks * 4 + l4) ^ (r & 7);
        bfr[nf] = *(const bf16x8*)&xb[r * FBK + ph * 8];
      }
#pragma unroll
      for (int mf = 0; mf < 4; ++mf)
#pragma unroll
        for (int nf = 0; nf < 4; ++nf)
          acc[mf][nf] = __builtin_amdgcn_mfma_f32_16x16x32_bf16(
              af[mf], bfr[nf], acc[mf][nf], 0, 0, 0);
    }
    if (dk == FNDK - 1) {
      const int ct = t >> 3;
#pragma unroll
      for (int mf = 0; mf < 4; ++mf) {
#pragma unroll
        for (int r = 0; r < 4; ++r) {
          const int code = ct * FBN + wm * 64 + mf * 16 + l4 * 4 + r;
          const float cn = snorm[code];
#pragma unroll
          for (int nf = 0; nf < 4; ++nf) {
            const float s = fmaf(-2.f, acc[mf][nf][r], cn);
            if (s < rmin[nf]) { rmin[nf] = s; ridx[nf] = code; }
          }
        }
      }
    }
    if (pre) write_tile(cur ^ 1, (t + 1) < FNDK);
    __syncthreads();
    cur ^= 1;
  }

#pragma unroll
  for (int m = 16; m <= 32; m <<= 1) {
#pragma unroll
    for (int nf = 0; nf < 4; ++nf) {
      const float om = __shfl_xor(rmin[nf], m, 64);
      const int oi = __shfl_xor(ridx[nf], m, 64);
      if (om < rmin[nf] || (om == rmin[nf] && oi < ridx[nf])) {
        rmin[nf] = om; ridx[nf] = oi;
      }
    }
  }
  if (l4 == 0) {
#pragma unroll
    for (int nf = 0; nf < 4; ++nf) {
      const int row = wn * 64 + nf * 16 + l15;
      redm[row][wm] = rmin[nf];
      redi[row][wm] = ridx[nf];
    }
  }
  __syncthreads();

  float tot = sq;
  if (tid < FBM) {
    float bm = redm[tid][0]; int bi = redi[tid][0];
#pragma unroll
    for (int c = 1; c < 4; ++c) {
      const float m_ = redm[tid][c]; const int i_ = redi[tid][c];
      if (m_ < bm || (m_ == bm && i_ < bi)) { bm = m_; bi = i_; }
    }
    idxs[tid] = bi;
    tot += bm;
  }
#pragma unroll
  for (int m = 1; m < 64; m <<= 1) tot += __shfl_xor(tot, m, 64);
  if (lane == 0) wpart[wid] = tot;
  __syncthreads();
  if (tid == 0) {
    double s = 0.0;
    for (int i = 0; i < 8; ++i) s += (double)wpart[i];
    atomicAdd(&lsum[blockIdx.x & 63], s);
  }

  for (int g = tid; g < FBM * (DIM / 4); g += FNT) {
    const int row = g >> 7;
    const int d4 = (g & 127) * 4;
    const int idx = idxs[row];
    *(float4*)&outq[(size_t)(row0 + row) * DIM + d4] =
        *(const float4*)&CB[(size_t)idx * DIM + d4];
  }
}

__global__ void vq_norms_kernel(const float* __restrict__ cb,
                                float* __restrict__ norms) {
  const int gw = (int)((blockIdx.x * blockDim.x + threadIdx.x) >> 6);
  const int l = threadIdx.x & 63;
  const float4 a = *(const float4*)&cb[(size_t)gw * DIM + l * 8];
  const float4 b = *(const float4*)&cb[(size_t)gw * DIM + l * 8 + 4];
  float s = a.x * a.x + a.y * a.y + a.z * a.z + a.w * a.w +
            b.x * b.x + b.y * b.y + b.z * b.z + b.w * b.w;
#pragma unroll
  for (int m = 1; m < 64; m <<= 1) s += __shfl_xor(s, m, 64);
  if (l == 0) norms[gw] = s;
}

__global__ void vq_finalize_kernel(const double* __restrict__ lsum,
                                   float* __restrict__ out) {
  double t = 0.0;
  for (int i = 0; i < 64; ++i) t += lsum[i];
  out[0] = (float)(1.25 * t / (double)((size_t)LAT_ROWS * DIM));
}

extern "C" void kernel_launch(void* const* d_in, const int* in_sizes, int n_in,
                              void* d_out, int out_size, void* d_ws, size_t ws_size,
                              hipStream_t stream) {
  const float* X = (const float*)d_in[0];     // [32768, 512] f32
  const float* CB = (const float*)d_in[1];    // [1024, 512] f32
  float* out = (float*)d_out;                 // quantized [16777216] + loss [1]
  double* lsum = (double*)((char*)d_ws + WS_LSUM);   // 64 doubles
  float* norms = (float*)((char*)d_ws + WS_NORM);    // 1024 f32

  hipMemsetAsync(d_ws, 0, 512, stream);
  if (ws_size >= WS_NEEDED) {
    long* CBf8 = (long*)((char*)d_ws + WS_CBF8);
    vq_prep17<<<256, NT, 0, stream>>>(CB, CBf8, norms);
    vq_main17<<<LAT_ROWS / BM, NT, 0, stream>>>(X, CBf8, CB, norms, out, lsum);
  } else {
    vq_norms_kernel<<<KCODES / 4, 256, 0, stream>>>(CB, norms);
    vq_main_fb<<<LAT_ROWS / FBM, FNT, 0, stream>>>(X, CB, norms, out, lsum);
  }
  vq_finalize_kernel<<<1, 1, 0, stream>>>(lsum, out + (size_t)LAT_ROWS * DIM);
}